// Round 6
// baseline (5917.559 us; speedup 1.0000x reference)
//
#include <hip/hip_runtime.h>

#define TSTEPS 784
#define BATCH  256
#define HDIM   512
#define NCLS   10
#define NGRP   16
#define WGPG   8

typedef __bf16 bf16x8 __attribute__((ext_vector_type(8)));
typedef float  f32x4  __attribute__((ext_vector_type(4)));
typedef unsigned uint4v __attribute__((ext_vector_type(4)));
typedef unsigned long long u64;
typedef unsigned short u16;

static __device__ __forceinline__ u16 f2bf(float f) {
  unsigned u = __builtin_bit_cast(unsigned, f);
  u += 0x7fffu + ((u >> 16) & 1u);
  return (u16)(u >> 16);
}
static __device__ __forceinline__ float bf2f(unsigned s) {
  unsigned u = s << 16;
  return __builtin_bit_cast(float, u);
}

// ---------------- xp[t][b] = inputs[b][perm[t]] ----------------
__global__ __launch_bounds__(256) void gather_xp(const float* __restrict__ in,
                                                 const int* __restrict__ perm,
                                                 float* __restrict__ xp) {
  int t = blockIdx.x;
  int b = threadIdx.x;
  int p = perm[t];
  p = (p < 0) ? 0 : (p >= TSTEPS ? TSTEPS - 1 : p);
  xp[t * BATCH + b] = in[b * TSTEPS + p];
}

// ---------------- X = (triu(W,1) - triu(W,1)^T) / 32 ----------------
__global__ __launch_bounds__(256) void build_X(const float* __restrict__ W,
                                               float* __restrict__ X) {
  int idx = blockIdx.x * 256 + threadIdx.x;
  int i = idx >> 9, j = idx & 511;
  float v = 0.f;
  if (j > i) v = W[i * HDIM + j];
  else if (i > j) v = -W[j * HDIM + i];
  X[idx] = v * 0.03125f;
}

// ---------------- P = coef*X + I ----------------
__global__ __launch_bounds__(256) void axpyI(float* __restrict__ P,
                                             const float* __restrict__ X, float coef) {
  int idx = blockIdx.x * 256 + threadIdx.x;
  int i = idx >> 9, j = idx & 511;
  P[idx] = coef * X[idx] + ((i == j) ? 1.f : 0.f);
}

// ---------------- C = alpha*A*B (+I), 512^3 fp32, 64x64 tile ----------------
// fp32 vector GEMM [R2-R8 proven]. The expm chain NEEDS fp32-class accuracy:
// split-bf16 here gave delta(Borth) ~1e-2 after 5 squarings -> absmax 12 (R9).
__global__ __launch_bounds__(256) void gemm512(float* __restrict__ C,
                                               const float* __restrict__ A,
                                               const float* __restrict__ B,
                                               float alpha, int addI) {
  __shared__ float As[16][68];
  __shared__ float Bs[16][68];
  const int tx = threadIdx.x, ty = threadIdx.y;
  const int tid = ty * 16 + tx;
  const int ib = blockIdx.y, jb = blockIdx.x;
  const int ra = tid >> 2, ca = (tid & 3) << 2;
  const int rb = tid >> 4, cb = (tid & 15) << 2;
  float acc[4][4] = {};
  for (int kt = 0; kt < HDIM / 16; ++kt) {
    f32x4 av = *(const f32x4*)(A + (ib * 64 + ra) * HDIM + kt * 16 + ca);
    f32x4 bv = *(const f32x4*)(B + (kt * 16 + rb) * HDIM + jb * 64 + cb);
    __syncthreads();
    As[ca + 0][ra] = av[0];
    As[ca + 1][ra] = av[1];
    As[ca + 2][ra] = av[2];
    As[ca + 3][ra] = av[3];
    *(f32x4*)&Bs[rb][cb] = bv;
    __syncthreads();
#pragma unroll
    for (int kk = 0; kk < 16; ++kk) {
      f32x4 a4 = *(const f32x4*)&As[kk][ty << 2];
      f32x4 b4 = *(const f32x4*)&Bs[kk][tx << 2];
#pragma unroll
      for (int u = 0; u < 4; ++u)
#pragma unroll
        for (int v = 0; v < 4; ++v) acc[u][v] = fmaf(a4[u], b4[v], acc[u][v]);
    }
  }
#pragma unroll
  for (int u = 0; u < 4; ++u)
#pragma unroll
    for (int v = 0; v < 4; ++v) {
      int r = ib * 64 + (ty << 2) + u, c = jb * 64 + (tx << 2) + v;
      float val = alpha * acc[u][v];
      if (addI && r == c) val += 1.f;
      C[r * HDIM + c] = val;
    }
}

// ---------------- persistent RNN scan [R15: tags + DIRECT fragment loads] ---
// R14 post-mortem: protocol correct (absmax 0.5) but slower than flags --
// kept the whole LDS round-trip (stage+barrier+32 conflicted b128 reads,
// SQ_LDS_BANK_CONFLICT 5.1e7) ON TOP of expensive full-32KB poll rounds.
// R15 collects the savings: each lane poll-loads EXACTLY its MFMA fragment
// dwords (row l16, cols ki*32+quad*8..+7) straight to registers -- 4
// dwordx4 per 64-col slice, one voffset + compile-time offset: immediates.
// Tag-check per slice (wave ballot), MFMA fresh, re-issue only stale.
// No LDS, no barriers, no flags, no drain; 4 waves fully decoupled.
// Own slice treated like remote (avoids runtime-indexed Bfh -> scratch).
// Tags/skew-safety/numerics identical to R14 (proven): u32 = hi|lo bf16,
// bit0 of lo = step tag (s>>1)&1; sc1 on all h loads/stores.
__global__ __launch_bounds__(256, 1) void rnn_main(
    const float* __restrict__ xp, const float* __restrict__ Borth,
    const float* __restrict__ W_in, const float* __restrict__ b_mod,
    const float* __restrict__ W_lin, const float* __restrict__ b_lin,
    unsigned* __restrict__ h0, unsigned* __restrict__ h1,
    float* __restrict__ out) {
  __shared__ unsigned tile0[8192];  // head staging only (32 KB)

  const int wg = blockIdx.x;
  const int gb = wg & 15;
  const int cg = wg >> 4;
  const int tid = threadIdx.x;
  const int wave = tid >> 6;
  const int lane = tid & 63;
  const int quad = lane >> 4;
  const int l16 = lane & 15;
  const int colg = (cg << 6) + (wave << 4) + l16;           // Bf column
  const int hbase = (cg << 6) + (wave << 4) + (quad << 2);  // epilogue h-col base

  // Borth fragments (round-hi split, R3-proven numerics)
  bf16x8 Bfh[16], Bfl[16];
#pragma unroll
  for (int ki = 0; ki < 16; ++ki) {
#pragma unroll
    for (int j = 0; j < 8; ++j) {
      int k = (ki << 5) + (quad << 3) + j;
      float v = Borth[k * HDIM + colg];
      u16 hb = f2bf(v);
      u16 lb = f2bf(v - bf2f(hb));
      Bfh[ki][j] = __builtin_bit_cast(__bf16, hb);
      Bfl[ki][j] = __builtin_bit_cast(__bf16, lb);
    }
  }
  const f32x4 win4 = *(const f32x4*)(W_in + hbase);
  const f32x4 bm4 = *(const f32x4*)(b_mod + hbase);

  const u64 b0 = (u64)(h0 + (gb << 13));  // 8192 u32 = 32 KB per group
  const u64 b1 = (u64)(h1 + (gb << 13));
  // fragment-load voffset (bytes): row l16 (2048 B) + col quad*8 u32 (32 B).
  // slice c, sub s, half h add the IMMEDIATE c*256 + s*128 + h*16.
  const unsigned rvoff = (unsigned)((l16 << 11) + (quad << 5));
  const unsigned soff = (unsigned)(((l16 << 9) + hbase) << 2);  // store byte off

  // slice registers (all compile-time-indexed; ~128 VGPR held)
  uint4v q00, q01, q02, q03, q10, q11, q12, q13;
  uint4v q20, q21, q22, q23, q30, q31, q32, q33;
  uint4v q40, q41, q42, q43, q50, q51, q52, q53;
  uint4v q60, q61, q62, q63, q70, q71, q72, q73;

#define ISSUE(c, O0, O1, O2, O3)                                          \
  asm volatile("global_load_dwordx4 %0, %4, %5 offset:" #O0 " sc1\n\t"    \
               "global_load_dwordx4 %1, %4, %5 offset:" #O1 " sc1\n\t"    \
               "global_load_dwordx4 %2, %4, %5 offset:" #O2 " sc1\n\t"    \
               "global_load_dwordx4 %3, %4, %5 offset:" #O3 " sc1"        \
               : "=&v"(q##c##0), "=&v"(q##c##1), "=&v"(q##c##2),          \
                 "=&v"(q##c##3)                                           \
               : "v"(rvoff), "s"(rb));
#define ISSUE_ALL                                                         \
  ISSUE(0, 0, 16, 128, 144)                                               \
  ISSUE(1, 256, 272, 384, 400)                                            \
  ISSUE(2, 512, 528, 640, 656)                                            \
  ISSUE(3, 768, 784, 896, 912)                                            \
  ISSUE(4, 1024, 1040, 1152, 1168)                                        \
  ISSUE(5, 1280, 1296, 1408, 1424)                                        \
  ISSUE(6, 1536, 1552, 1664, 1680)                                        \
  ISSUE(7, 1792, 1808, 1920, 1936)
#define REISSUE(c, O0, O1, O2, O3)                                        \
  if (pend & (1u << c)) { ISSUE(c, O0, O1, O2, O3) }
#define REISSUE_ALL                                                       \
  REISSUE(0, 0, 16, 128, 144)                                             \
  REISSUE(1, 256, 272, 384, 400)                                          \
  REISSUE(2, 512, 528, 640, 656)                                          \
  REISSUE(3, 768, 784, 896, 912)                                          \
  REISSUE(4, 1024, 1040, 1152, 1168)                                      \
  REISSUE(5, 1280, 1296, 1408, 1424)                                      \
  REISSUE(6, 1536, 1552, 1664, 1680)                                      \
  REISSUE(7, 1792, 1808, 1920, 1936)

  // perm split + 3 split-bf16 MFMAs for one ki (E0 = j0..3, E1 = j4..7)
#define MFMA_HALF(E0, E1, KI)                                             \
  {                                                                       \
    uint4v ahv, alv;                                                      \
    ahv[0] = __builtin_amdgcn_perm(E0[1], E0[0], 0x07060302u);            \
    ahv[1] = __builtin_amdgcn_perm(E0[3], E0[2], 0x07060302u);            \
    ahv[2] = __builtin_amdgcn_perm(E1[1], E1[0], 0x07060302u);            \
    ahv[3] = __builtin_amdgcn_perm(E1[3], E1[2], 0x07060302u);            \
    alv[0] = __builtin_amdgcn_perm(E0[1], E0[0], 0x05040100u);            \
    alv[1] = __builtin_amdgcn_perm(E0[3], E0[2], 0x05040100u);            \
    alv[2] = __builtin_amdgcn_perm(E1[1], E1[0], 0x05040100u);            \
    alv[3] = __builtin_amdgcn_perm(E1[3], E1[2], 0x05040100u);            \
    bf16x8 ah = __builtin_bit_cast(bf16x8, ahv);                          \
    bf16x8 al = __builtin_bit_cast(bf16x8, alv);                          \
    hh = __builtin_amdgcn_mfma_f32_16x16x32_bf16(Bfh[KI], ah, hh, 0, 0, 0); \
    lh = __builtin_amdgcn_mfma_f32_16x16x32_bf16(Bfh[KI], al, lh, 0, 0, 0); \
    hl = __builtin_amdgcn_mfma_f32_16x16x32_bf16(Bfl[KI], ah, hl, 0, 0, 0); \
  }
#define PROC(c)                                                           \
  if (pend & (1u << c)) {                                                 \
    unsigned orv = (q##c##0[0] ^ rmask) | (q##c##0[1] ^ rmask) |          \
                   (q##c##0[2] ^ rmask) | (q##c##0[3] ^ rmask) |          \
                   (q##c##1[0] ^ rmask) | (q##c##1[1] ^ rmask) |          \
                   (q##c##1[2] ^ rmask) | (q##c##1[3] ^ rmask) |          \
                   (q##c##2[0] ^ rmask) | (q##c##2[1] ^ rmask) |          \
                   (q##c##2[2] ^ rmask) | (q##c##2[3] ^ rmask) |          \
                   (q##c##3[0] ^ rmask) | (q##c##3[1] ^ rmask) |          \
                   (q##c##3[2] ^ rmask) | (q##c##3[3] ^ rmask);           \
    if (__ballot((orv & 1u) == 0u) == ~0ull) {                            \
      MFMA_HALF(q##c##0, q##c##1, 2 * c)                                  \
      MFMA_HALF(q##c##2, q##c##3, 2 * c + 1)                              \
      pend &= ~(1u << c);                                                 \
    }                                                                     \
  }

  for (int t = 0; t < TSTEPS; ++t) {
    const u64 rb = (t & 1) ? b1 : b0;
    const u64 wb = (t & 1) ? b0 : b1;
    const unsigned rmask = ((t >> 1) & 1) ? 0xFFFFFFFFu : 0u;
    const unsigned wtag = (unsigned)(((t + 1) >> 1) & 1);

    const float xs = xp[t * BATCH + (gb << 4) + l16];

    f32x4 hh = {0.f, 0.f, 0.f, 0.f};
    f32x4 lh = {0.f, 0.f, 0.f, 0.f};
    f32x4 hl = {0.f, 0.f, 0.f, 0.f};

    ISSUE_ALL
    asm volatile("s_waitcnt vmcnt(0)" ::: "memory");
    __builtin_amdgcn_sched_barrier(0);

    unsigned pend = 0xffu;
    int spin = 0;
    for (;;) {
      PROC(0) PROC(1) PROC(2) PROC(3) PROC(4) PROC(5) PROC(6) PROC(7)
      if (!pend) break;
      if (++spin > (1 << 11)) break;  // diagnosability valve
      __builtin_amdgcn_s_sleep(1);
      REISSUE_ALL
      asm volatile("s_waitcnt vmcnt(0)" ::: "memory");
      __builtin_amdgcn_sched_barrier(0);
    }

    // ---- epilogue: D = pre^T (thread: batchrow=l16, h-cols hbase..+3) ----
    {
      uint4v sv;
#pragma unroll
      for (int r = 0; r < 4; ++r) {
        float pre = hh[r] + lh[r] + hl[r] + xs * win4[r];
        float mm = fmaxf(fabsf(pre) + bm4[r], 0.f);
        float hv = (pre > 0.f) ? mm : ((pre < 0.f) ? -mm : 0.f);
        u16 hbv = f2bf(hv);
        u16 lbv = f2bf(hv - bf2f(hbv));
        sv[r] = ((unsigned)hbv << 16) | (unsigned)((lbv & 0xFFFEu) | wtag);
      }
      asm volatile("global_store_dwordx4 %[o], %[d], %[b] sc1" ::[o] "v"(soff),
                   [d] "v"(sv), [b] "s"(wb));
    }
    // no drain, no flag: tags + coherence order cover the 1-step-skew
    // overwrite hazard (R14-proven).
  }

  // ---- head: h_784 in buffer 0 (tag 0); poll + LDS stage + dot [R14] ----
  if (cg == 0) {
    const unsigned vo0 = (unsigned)((tid + 0 * 256) << 4);
    const unsigned vo1 = (unsigned)((tid + 1 * 256) << 4);
    const unsigned vo2 = (unsigned)((tid + 2 * 256) << 4);
    const unsigned vo3 = (unsigned)((tid + 3 * 256) << 4);
    const unsigned vo4 = (unsigned)((tid + 4 * 256) << 4);
    const unsigned vo5 = (unsigned)((tid + 5 * 256) << 4);
    const unsigned vo6 = (unsigned)((tid + 6 * 256) << 4);
    const unsigned vo7 = (unsigned)((tid + 7 * 256) << 4);
    uint4v p0, p1, p2, p3, p4, p5, p6, p7;
    int spin = 0;
    for (;;) {
      asm volatile(
          "global_load_dwordx4 %[q0], %[v0], %[b] sc1\n\t"
          "global_load_dwordx4 %[q1], %[v1], %[b] sc1\n\t"
          "global_load_dwordx4 %[q2], %[v2], %[b] sc1\n\t"
          "global_load_dwordx4 %[q3], %[v3], %[b] sc1\n\t"
          "global_load_dwordx4 %[q4], %[v4], %[b] sc1\n\t"
          "global_load_dwordx4 %[q5], %[v5], %[b] sc1\n\t"
          "global_load_dwordx4 %[q6], %[v6], %[b] sc1\n\t"
          "global_load_dwordx4 %[q7], %[v7], %[b] sc1\n\t"
          "s_waitcnt vmcnt(0)"
          : [q0] "=&v"(p0), [q1] "=&v"(p1), [q2] "=&v"(p2), [q3] "=&v"(p3),
            [q4] "=&v"(p4), [q5] "=&v"(p5), [q6] "=&v"(p6), [q7] "=&v"(p7)
          : [v0] "v"(vo0), [v1] "v"(vo1), [v2] "v"(vo2), [v3] "v"(vo3),
            [v4] "v"(vo4), [v5] "v"(vo5), [v6] "v"(vo6), [v7] "v"(vo7),
            [b] "s"(b0));
      unsigned bad = 0;
#define TCHK(q) bad |= q[0] | q[1] | q[2] | q[3]
      TCHK(p0); TCHK(p1); TCHK(p2); TCHK(p3);
      TCHK(p4); TCHK(p5); TCHK(p6); TCHK(p7);
#undef TCHK
      if (!(bad & 1u)) break;
      __builtin_amdgcn_s_sleep(1);
      if (++spin > (1 << 11)) break;
    }
    __builtin_amdgcn_sched_barrier(0);
#define STG(g, q)                                                      \
  {                                                                    \
    int G = tid + ((g) << 8);                                          \
    int r = G >> 7;                                                    \
    unsigned dc = (unsigned)(G & 127) << 2;                            \
    unsigned phys = ((unsigned)r << 9) | (dc ^ ((unsigned)(r & 7) << 2)); \
    *(uint4v*)(tile0 + phys) = q;                                      \
  }
    STG(0, p0) STG(1, p1) STG(2, p2) STG(3, p3)
    STG(4, p4) STG(5, p5) STG(6, p6) STG(7, p7)
#undef STG
    __syncthreads();
    int row = tid >> 4;
    int cls = tid & 15;
    if (cls < NCLS) {
      float acc = b_lin[cls];
      const float* wl = W_lin + cls * HDIM;
      for (int k = 0; k < HDIM; ++k) {
        unsigned phys = ((unsigned)row << 9) |
                        ((unsigned)k ^ (((unsigned)row & 7) << 2));
        unsigned x = tile0[phys];
        float hv = bf2f(x >> 16) + bf2f(x & 0xFFFFu);
        acc = fmaf(hv, wl[k], acc);
      }
      out[((gb << 4) + row) * NCLS + cls] = acc;
    }
  }
}

extern "C" void kernel_launch(void* const* d_in, const int* in_sizes, int n_in,
                              void* d_out, int out_size, void* d_ws, size_t ws_size,
                              hipStream_t stream) {
  const float* inputs = (const float*)d_in[0];  // 256x784
  const int* perm = (const int*)d_in[1];        // 784 (int64 -> int32 by harness)
  const float* W_skew = (const float*)d_in[2];  // 512x512
  const float* W_in = (const float*)d_in[3];    // 512
  const float* b_mod = (const float*)d_in[4];   // 512
  const float* W_lin = (const float*)d_in[5];   // 10x512
  const float* b_lin = (const float*)d_in[6];   // 10
  float* out = (float*)d_out;

  char* ws = (char*)d_ws;
  unsigned* h0 = (unsigned*)ws;               // 512 KB (packed hi|lo u32)
  unsigned* h1 = h0 + BATCH * HDIM;           // 512 KB
  float* xp = (float*)(h1 + BATCH * HDIM);    // 0.77 MB
  float* X = xp + TSTEPS * BATCH;             // 1 MB
  float* P = X + HDIM * HDIM;                 // 1 MB
  float* Q = P + HDIM * HDIM;                 // 1 MB (total ~4.8 MB)

  // h0 = zeros, tag bit 0 -> valid for t=0 (h0 IS zero).
  // h1 = 0x01010101 -> tag bit 1 = INVALID for first read (t=1 expects 0).
  hipMemsetAsync(h0, 0, (size_t)BATCH * HDIM * 4, stream);
  hipMemsetAsync(h1, 0x01, (size_t)BATCH * HDIM * 4, stream);

  gather_xp<<<TSTEPS, 256, 0, stream>>>(inputs, perm, xp);
  build_X<<<(HDIM * HDIM) / 256, 256, 0, stream>>>(W_skew, X);

  // expm(A) = (T6(A/32))^(2^5), Horner -- fp32 gemm512 [R2-R8 proven numerics]
  axpyI<<<(HDIM * HDIM) / 256, 256, 0, stream>>>(P, X, 1.f / 6.f);
  float* a = P;
  float* b = Q;
  for (int k = 5; k >= 1; --k) {
    gemm512<<<dim3(8, 8), dim3(16, 16), 0, stream>>>(b, X, a, 1.f / (float)k, 1);
    float* tmp = a; a = b; b = tmp;
  }
  for (int i = 0; i < 5; ++i) {
    gemm512<<<dim3(8, 8), dim3(16, 16), 0, stream>>>(b, a, a, 1.f, 0);
    float* tmp = a; a = b; b = tmp;
  }
  // a == P (10 swaps -> back to P)

  rnn_main<<<NGRP * WGPG, 256, 0, stream>>>(xp, a, W_in, b_mod, W_lin, b_lin,
                                            h0, h1, out);
  (void)in_sizes; (void)n_in; (void)out_size; (void)ws_size;
}

// Round 7
// 4351.690 us; speedup vs baseline: 1.3598x; 1.3598x over previous
//
#include <hip/hip_runtime.h>

#define TSTEPS 784
#define BATCH  256
#define HDIM   512
#define NCLS   10
#define NGRP   16
#define WGPG   8

typedef __bf16 bf16x8 __attribute__((ext_vector_type(8)));
typedef float  f32x4  __attribute__((ext_vector_type(4)));
typedef unsigned uint4v __attribute__((ext_vector_type(4)));
typedef unsigned long long u64;
typedef unsigned short u16;

static __device__ __forceinline__ u16 f2bf(float f) {
  unsigned u = __builtin_bit_cast(unsigned, f);
  u += 0x7fffu + ((u >> 16) & 1u);
  return (u16)(u >> 16);
}
static __device__ __forceinline__ float bf2f(unsigned s) {
  unsigned u = s << 16;
  return __builtin_bit_cast(float, u);
}

// ---------------- xp[t][b] = inputs[b][perm[t]] ----------------
__global__ __launch_bounds__(256) void gather_xp(const float* __restrict__ in,
                                                 const int* __restrict__ perm,
                                                 float* __restrict__ xp) {
  int t = blockIdx.x;
  int b = threadIdx.x;
  int p = perm[t];
  p = (p < 0) ? 0 : (p >= TSTEPS ? TSTEPS - 1 : p);
  xp[t * BATCH + b] = in[b * TSTEPS + p];
}

// ---------------- X = (triu(W,1) - triu(W,1)^T) / 32 ----------------
__global__ __launch_bounds__(256) void build_X(const float* __restrict__ W,
                                               float* __restrict__ X) {
  int idx = blockIdx.x * 256 + threadIdx.x;
  int i = idx >> 9, j = idx & 511;
  float v = 0.f;
  if (j > i) v = W[i * HDIM + j];
  else if (i > j) v = -W[j * HDIM + i];
  X[idx] = v * 0.03125f;
}

// ---------------- P = coef*X + I ----------------
__global__ __launch_bounds__(256) void axpyI(float* __restrict__ P,
                                             const float* __restrict__ X, float coef) {
  int idx = blockIdx.x * 256 + threadIdx.x;
  int i = idx >> 9, j = idx & 511;
  P[idx] = coef * X[idx] + ((i == j) ? 1.f : 0.f);
}

// ---------------- C = alpha*A*B (+I), 512^3 fp32, 64x64 tile ----------------
// fp32 vector GEMM [R2-R8 proven]. The expm chain NEEDS fp32-class accuracy:
// split-bf16 here gave delta(Borth) ~1e-2 after 5 squarings -> absmax 12 (R9).
__global__ __launch_bounds__(256) void gemm512(float* __restrict__ C,
                                               const float* __restrict__ A,
                                               const float* __restrict__ B,
                                               float alpha, int addI) {
  __shared__ float As[16][68];
  __shared__ float Bs[16][68];
  const int tx = threadIdx.x, ty = threadIdx.y;
  const int tid = ty * 16 + tx;
  const int ib = blockIdx.y, jb = blockIdx.x;
  const int ra = tid >> 2, ca = (tid & 3) << 2;
  const int rb = tid >> 4, cb = (tid & 15) << 2;
  float acc[4][4] = {};
  for (int kt = 0; kt < HDIM / 16; ++kt) {
    f32x4 av = *(const f32x4*)(A + (ib * 64 + ra) * HDIM + kt * 16 + ca);
    f32x4 bv = *(const f32x4*)(B + (kt * 16 + rb) * HDIM + jb * 64 + cb);
    __syncthreads();
    As[ca + 0][ra] = av[0];
    As[ca + 1][ra] = av[1];
    As[ca + 2][ra] = av[2];
    As[ca + 3][ra] = av[3];
    *(f32x4*)&Bs[rb][cb] = bv;
    __syncthreads();
#pragma unroll
    for (int kk = 0; kk < 16; ++kk) {
      f32x4 a4 = *(const f32x4*)&As[kk][ty << 2];
      f32x4 b4 = *(const f32x4*)&Bs[kk][tx << 2];
#pragma unroll
      for (int u = 0; u < 4; ++u)
#pragma unroll
        for (int v = 0; v < 4; ++v) acc[u][v] = fmaf(a4[u], b4[v], acc[u][v]);
    }
  }
#pragma unroll
  for (int u = 0; u < 4; ++u)
#pragma unroll
    for (int v = 0; v < 4; ++v) {
      int r = ib * 64 + (ty << 2) + u, c = jb * 64 + (tx << 2) + v;
      float val = alpha * acc[u][v];
      if (addI && r == c) val += 1.f;
      C[r * HDIM + c] = val;
    }
}

// ---------------- persistent RNN scan [R16: tags + LDS + cheap retry] -------
// Ledger: R6 flags = 2250us (drain+flag+poll serialize, ~1300-1900cy/step).
// R14 tags+LDS = 2670us (protocol correct, retries cost full 32KB+sleep).
// R15 direct-load = 5614us (lost LDS sharing: 4 waves x full reload).
// R16 composes the proven pieces: R14's LDS-staged tagged protocol (one
// cooperative 32KB load, 4 waves share via LDS) + R15's pend-masked retry
// (re-load ONLY stale 16B granules, no sleep) + early issue: step t+1's 8
// poll-loads are issued at the BOTTOM of step t right after the epilogue
// store (sound: tags self-validate any interleaving; store ack and load
// return drain concurrently under one vmcnt(0)). Head reuses the final
// in-flight loads. Tags: u32 = (hi_bf16<<16)|lo_bf16, bit0 of lo = step
// tag (s>>1)&1; sc1 (device scope) on all h traffic. Skew>1 impossible
// (chain dependency + per-location coherence order) [R14-proven].
__global__ __launch_bounds__(256, 1) void rnn_main(
    const float* __restrict__ xp, const float* __restrict__ Borth,
    const float* __restrict__ W_in, const float* __restrict__ b_mod,
    const float* __restrict__ W_lin, const float* __restrict__ b_lin,
    unsigned* __restrict__ h0, unsigned* __restrict__ h1,
    float* __restrict__ out) {
  __shared__ unsigned tile0[8192], tile1[8192];  // 32 KB x 2 (double buffer)

  const int wg = blockIdx.x;
  const int gb = wg & 15;
  const int cg = wg >> 4;
  const int tid = threadIdx.x;
  const int wave = tid >> 6;
  const int lane = tid & 63;
  const int quad = lane >> 4;
  const int l16 = lane & 15;
  const int colg = (cg << 6) + (wave << 4) + l16;           // Bf column
  const int hbase = (cg << 6) + (wave << 4) + (quad << 2);  // epilogue h-col base

  // Borth fragments (round-hi split, R3-proven numerics)
  bf16x8 Bfh[16], Bfl[16];
#pragma unroll
  for (int ki = 0; ki < 16; ++ki) {
#pragma unroll
    for (int j = 0; j < 8; ++j) {
      int k = (ki << 5) + (quad << 3) + j;
      float v = Borth[k * HDIM + colg];
      u16 hb = f2bf(v);
      u16 lb = f2bf(v - bf2f(hb));
      Bfh[ki][j] = __builtin_bit_cast(__bf16, hb);
      Bfl[ki][j] = __builtin_bit_cast(__bf16, lb);
    }
  }
  const f32x4 win4 = *(const f32x4*)(W_in + hbase);
  const f32x4 bm4 = *(const f32x4*)(b_mod + hbase);

  const u64 b0 = (u64)(h0 + (gb << 13));  // 8192 u32 = 32 KB per group
  const u64 b1 = (u64)(h1 + (gb << 13));
  // poll voffsets: granule g = tid + g*256 -> byte off *16
  const unsigned vo0 = (unsigned)((tid + 0 * 256) << 4);
  const unsigned vo1 = (unsigned)((tid + 1 * 256) << 4);
  const unsigned vo2 = (unsigned)((tid + 2 * 256) << 4);
  const unsigned vo3 = (unsigned)((tid + 3 * 256) << 4);
  const unsigned vo4 = (unsigned)((tid + 4 * 256) << 4);
  const unsigned vo5 = (unsigned)((tid + 5 * 256) << 4);
  const unsigned vo6 = (unsigned)((tid + 6 * 256) << 4);
  const unsigned vo7 = (unsigned)((tid + 7 * 256) << 4);
  const unsigned soff = (unsigned)(((l16 << 9) + hbase) << 2);  // store byte off
  const unsigned swz = (unsigned)((l16 & 7) << 2);

  uint4v q0, q1, q2, q3, q4, q5, q6, q7;

#define ISSUE_ALL(B)                                                        \
  asm volatile("global_load_dwordx4 %[q0], %[v0], %[b] sc1\n\t"             \
               "global_load_dwordx4 %[q1], %[v1], %[b] sc1\n\t"             \
               "global_load_dwordx4 %[q2], %[v2], %[b] sc1\n\t"             \
               "global_load_dwordx4 %[q3], %[v3], %[b] sc1\n\t"             \
               "global_load_dwordx4 %[q4], %[v4], %[b] sc1\n\t"             \
               "global_load_dwordx4 %[q5], %[v5], %[b] sc1\n\t"             \
               "global_load_dwordx4 %[q6], %[v6], %[b] sc1\n\t"             \
               "global_load_dwordx4 %[q7], %[v7], %[b] sc1"                 \
               : [q0] "=&v"(q0), [q1] "=&v"(q1), [q2] "=&v"(q2),            \
                 [q3] "=&v"(q3), [q4] "=&v"(q4), [q5] "=&v"(q5),            \
                 [q6] "=&v"(q6), [q7] "=&v"(q7)                             \
               : [v0] "v"(vo0), [v1] "v"(vo1), [v2] "v"(vo2),               \
                 [v3] "v"(vo3), [v4] "v"(vo4), [v5] "v"(vo5),               \
                 [v6] "v"(vo6), [v7] "v"(vo7), [b] "s"(B));
#define CHKG(g)                                                             \
  if (pend & (1u << g)) {                                                   \
    unsigned orv = (q##g[0] ^ rmask) | (q##g[1] ^ rmask) |                  \
                   (q##g[2] ^ rmask) | (q##g[3] ^ rmask);                   \
    if (!(orv & 1u)) pend &= ~(1u << g);                                    \
  }
#define RLDG(g, B)                                                          \
  if (pend & (1u << g))                                                     \
    asm volatile("global_load_dwordx4 %0, %1, %2 sc1"                       \
                 : "=&v"(q##g) : "v"(vo##g), "s"(B));
#define STG(g, q, TL)                                                       \
  {                                                                         \
    int G = tid + ((g) << 8);                                               \
    int r = G >> 7;                                                         \
    unsigned dc = (unsigned)(G & 127) << 2;                                 \
    unsigned phys = ((unsigned)r << 9) | (dc ^ ((unsigned)(r & 7) << 2));   \
    *(uint4v*)(TL + phys) = q;                                              \
  }

  // prologue: first-step loads in flight before the loop
  ISSUE_ALL(b0)

  for (int t = 0; t < TSTEPS; ++t) {
    const u64 rb = (t & 1) ? b1 : b0;
    const u64 wb = (t & 1) ? b0 : b1;
    const unsigned rmask = ((t >> 1) & 1) ? 0xFFFFFFFFu : 0u;
    const unsigned wtag = (unsigned)(((t + 1) >> 1) & 1);
    unsigned* const tl = (t & 1) ? tile1 : tile0;

    const float xs = xp[t * BATCH + (gb << 4) + l16];  // early, hides under poll

    // ---- tagged poll: loads already in flight; retry ONLY stale granules --
    unsigned pend = 0xffu;
    int spin = 0;
    for (;;) {
      asm volatile("s_waitcnt vmcnt(0)" ::: "memory");
      __builtin_amdgcn_sched_barrier(0);  // rule #18: pin checks below wait
      CHKG(0) CHKG(1) CHKG(2) CHKG(3) CHKG(4) CHKG(5) CHKG(6) CHKG(7)
      if (!pend) break;
      if (++spin > (1 << 11)) break;  // diagnosability valve
      RLDG(0, rb) RLDG(1, rb) RLDG(2, rb) RLDG(3, rb)
      RLDG(4, rb) RLDG(5, rb) RLDG(6, rb) RLDG(7, rb)
    }

    // ---- LDS stage (swizzled: phys = row<<9 | (dcol ^ ((row&7)<<2))) ----
    STG(0, q0, tl) STG(1, q1, tl) STG(2, q2, tl) STG(3, q3, tl)
    STG(4, q4, tl) STG(5, q5, tl) STG(6, q6, tl) STG(7, q7, tl)
    __syncthreads();

    // ---- fragment reads + perm hi/lo split + swapped split-bf16 MFMA ----
    // second granule at (dc0+4)^swz [R14 fix, proven]
    f32x4 hh = {0.f, 0.f, 0.f, 0.f};
    f32x4 lh = {0.f, 0.f, 0.f, 0.f};
    f32x4 hl = {0.f, 0.f, 0.f, 0.f};
#pragma unroll
    for (int ki = 0; ki < 16; ++ki) {
      unsigned dc0 = (unsigned)((ki << 5) + (quad << 3));
      unsigned base = (unsigned)l16 << 9;
      unsigned offL = base + (dc0 ^ swz);
      unsigned offH = base + ((dc0 + 4) ^ swz);
      uint4v e0 = *(const uint4v*)(tl + offL);
      uint4v e1 = *(const uint4v*)(tl + offH);
      uint4v ahv, alv;
      ahv[0] = __builtin_amdgcn_perm(e0[1], e0[0], 0x07060302u);
      ahv[1] = __builtin_amdgcn_perm(e0[3], e0[2], 0x07060302u);
      ahv[2] = __builtin_amdgcn_perm(e1[1], e1[0], 0x07060302u);
      ahv[3] = __builtin_amdgcn_perm(e1[3], e1[2], 0x07060302u);
      alv[0] = __builtin_amdgcn_perm(e0[1], e0[0], 0x05040100u);
      alv[1] = __builtin_amdgcn_perm(e0[3], e0[2], 0x05040100u);
      alv[2] = __builtin_amdgcn_perm(e1[1], e1[0], 0x05040100u);
      alv[3] = __builtin_amdgcn_perm(e1[3], e1[2], 0x05040100u);
      bf16x8 ah = __builtin_bit_cast(bf16x8, ahv);
      bf16x8 al = __builtin_bit_cast(bf16x8, alv);
      hh = __builtin_amdgcn_mfma_f32_16x16x32_bf16(Bfh[ki], ah, hh, 0, 0, 0);
      lh = __builtin_amdgcn_mfma_f32_16x16x32_bf16(Bfh[ki], al, lh, 0, 0, 0);
      hl = __builtin_amdgcn_mfma_f32_16x16x32_bf16(Bfl[ki], ah, hl, 0, 0, 0);
    }

    // ---- epilogue: D = pre^T (thread: batchrow=l16, h-cols hbase..+3) ----
    {
      uint4v sv;
#pragma unroll
      for (int r = 0; r < 4; ++r) {
        float pre = hh[r] + lh[r] + hl[r] + xs * win4[r];
        float mm = fmaxf(fabsf(pre) + bm4[r], 0.f);
        float hv = (pre > 0.f) ? mm : ((pre < 0.f) ? -mm : 0.f);
        u16 hbv = f2bf(hv);
        u16 lbv = f2bf(hv - bf2f(hbv));
        sv[r] = ((unsigned)hbv << 16) | (unsigned)((lbv & 0xFFFEu) | wtag);
      }
      asm volatile("global_store_dwordx4 %[o], %[d], %[b] sc1" ::[o] "v"(soff),
                   [d] "v"(sv), [b] "s"(wb));
    }

    // ---- early issue of NEXT step's poll loads (rb(t+1) == wb(t)):
    // overlaps load latency with the store's LLC trip; tags make any
    // interleaving safe. Last iteration's issue prefetches the head read.
    ISSUE_ALL(wb)
  }

  // ---- head: h_784 in buffer 0 (tag (784>>1)&1 = 0); loads already in
  // flight from t=783's early issue (wb(783) == b0). ----
  if (cg == 0) {
    const unsigned rmask = 0u;
    unsigned pend = 0xffu;
    int spin = 0;
    for (;;) {
      asm volatile("s_waitcnt vmcnt(0)" ::: "memory");
      __builtin_amdgcn_sched_barrier(0);
      CHKG(0) CHKG(1) CHKG(2) CHKG(3) CHKG(4) CHKG(5) CHKG(6) CHKG(7)
      if (!pend) break;
      if (++spin > (1 << 11)) break;
      RLDG(0, b0) RLDG(1, b0) RLDG(2, b0) RLDG(3, b0)
      RLDG(4, b0) RLDG(5, b0) RLDG(6, b0) RLDG(7, b0)
    }
    STG(0, q0, tile0) STG(1, q1, tile0) STG(2, q2, tile0) STG(3, q3, tile0)
    STG(4, q4, tile0) STG(5, q5, tile0) STG(6, q6, tile0) STG(7, q7, tile0)
    __syncthreads();
    int row = tid >> 4;
    int cls = tid & 15;
    if (cls < NCLS) {
      float acc = b_lin[cls];
      const float* wl = W_lin + cls * HDIM;
      for (int k = 0; k < HDIM; ++k) {
        unsigned phys = ((unsigned)row << 9) |
                        ((unsigned)k ^ (((unsigned)row & 7) << 2));
        unsigned x = tile0[phys];
        float hv = bf2f(x >> 16) + bf2f(x & 0xFFFFu);
        acc = fmaf(hv, wl[k], acc);
      }
      out[((gb << 4) + row) * NCLS + cls] = acc;
    }
  }
}

extern "C" void kernel_launch(void* const* d_in, const int* in_sizes, int n_in,
                              void* d_out, int out_size, void* d_ws, size_t ws_size,
                              hipStream_t stream) {
  const float* inputs = (const float*)d_in[0];  // 256x784
  const int* perm = (const int*)d_in[1];        // 784 (int64 -> int32 by harness)
  const float* W_skew = (const float*)d_in[2];  // 512x512
  const float* W_in = (const float*)d_in[3];    // 512
  const float* b_mod = (const float*)d_in[4];   // 512
  const float* W_lin = (const float*)d_in[5];   // 10x512
  const float* b_lin = (const float*)d_in[6];   // 10
  float* out = (float*)d_out;

  char* ws = (char*)d_ws;
  unsigned* h0 = (unsigned*)ws;               // 512 KB (packed hi|lo u32)
  unsigned* h1 = h0 + BATCH * HDIM;           // 512 KB
  float* xp = (float*)(h1 + BATCH * HDIM);    // 0.77 MB
  float* X = xp + TSTEPS * BATCH;             // 1 MB
  float* P = X + HDIM * HDIM;                 // 1 MB
  float* Q = P + HDIM * HDIM;                 // 1 MB (total ~4.8 MB)

  // h0 = zeros, tag bit 0 -> valid for t=0 (h0 IS zero).
  // h1 = 0x01010101 -> tag bit 1 = INVALID for first read (t=1 expects 0).
  hipMemsetAsync(h0, 0, (size_t)BATCH * HDIM * 4, stream);
  hipMemsetAsync(h1, 0x01, (size_t)BATCH * HDIM * 4, stream);

  gather_xp<<<TSTEPS, 256, 0, stream>>>(inputs, perm, xp);
  build_X<<<(HDIM * HDIM) / 256, 256, 0, stream>>>(W_skew, X);

  // expm(A) = (T6(A/32))^(2^5), Horner -- fp32 gemm512 [R2-R8 proven numerics]
  axpyI<<<(HDIM * HDIM) / 256, 256, 0, stream>>>(P, X, 1.f / 6.f);
  float* a = P;
  float* b = Q;
  for (int k = 5; k >= 1; --k) {
    gemm512<<<dim3(8, 8), dim3(16, 16), 0, stream>>>(b, X, a, 1.f / (float)k, 1);
    float* tmp = a; a = b; b = tmp;
  }
  for (int i = 0; i < 5; ++i) {
    gemm512<<<dim3(8, 8), dim3(16, 16), 0, stream>>>(b, a, a, 1.f, 0);
    float* tmp = a; a = b; b = tmp;
  }
  // a == P (10 swaps -> back to P)

  rnn_main<<<NGRP * WGPG, 256, 0, stream>>>(xp, a, W_in, b_mod, W_lin, b_lin,
                                            h0, h1, out);
  (void)in_sizes; (void)n_in; (void)out_size; (void)ws_size;
}

// Round 8
// 2736.334 us; speedup vs baseline: 2.1626x; 1.5903x over previous
//
#include <hip/hip_runtime.h>

#define TSTEPS 784
#define BATCH  256
#define HDIM   512
#define NCLS   10
#define NGRP   16
#define WGPG   8

typedef __bf16 bf16x8 __attribute__((ext_vector_type(8)));
typedef float  f32x4  __attribute__((ext_vector_type(4)));
typedef unsigned uint4v __attribute__((ext_vector_type(4)));
typedef unsigned long long u64;
typedef unsigned short u16;

static __device__ __forceinline__ u16 f2bf(float f) {
  unsigned u = __builtin_bit_cast(unsigned, f);
  u += 0x7fffu + ((u >> 16) & 1u);
  return (u16)(u >> 16);
}
static __device__ __forceinline__ float bf2f(unsigned s) {
  unsigned u = s << 16;
  return __builtin_bit_cast(float, u);
}

// ---------------- xp[t][b] = inputs[b][perm[t]] ----------------
__global__ __launch_bounds__(256) void gather_xp(const float* __restrict__ in,
                                                 const int* __restrict__ perm,
                                                 float* __restrict__ xp) {
  int t = blockIdx.x;
  int b = threadIdx.x;
  int p = perm[t];
  p = (p < 0) ? 0 : (p >= TSTEPS ? TSTEPS - 1 : p);
  xp[t * BATCH + b] = in[b * TSTEPS + p];
}

// ---------------- X = (triu(W,1) - triu(W,1)^T) / 32 ----------------
__global__ __launch_bounds__(256) void build_X(const float* __restrict__ W,
                                               float* __restrict__ X) {
  int idx = blockIdx.x * 256 + threadIdx.x;
  int i = idx >> 9, j = idx & 511;
  float v = 0.f;
  if (j > i) v = W[i * HDIM + j];
  else if (i > j) v = -W[j * HDIM + i];
  X[idx] = v * 0.03125f;
}

// ---------------- P = coef*X + I ----------------
__global__ __launch_bounds__(256) void axpyI(float* __restrict__ P,
                                             const float* __restrict__ X, float coef) {
  int idx = blockIdx.x * 256 + threadIdx.x;
  int i = idx >> 9, j = idx & 511;
  P[idx] = coef * X[idx] + ((i == j) ? 1.f : 0.f);
}

// ---------------- C = alpha*A*B (+I), 512^3 fp32, 64x64 tile ----------------
// fp32 vector GEMM [R2-R8 proven]. The expm chain NEEDS fp32-class accuracy:
// split-bf16 here gave delta(Borth) ~1e-2 after 5 squarings -> absmax 12 (R9).
__global__ __launch_bounds__(256) void gemm512(float* __restrict__ C,
                                               const float* __restrict__ A,
                                               const float* __restrict__ B,
                                               float alpha, int addI) {
  __shared__ float As[16][68];
  __shared__ float Bs[16][68];
  const int tx = threadIdx.x, ty = threadIdx.y;
  const int tid = ty * 16 + tx;
  const int ib = blockIdx.y, jb = blockIdx.x;
  const int ra = tid >> 2, ca = (tid & 3) << 2;
  const int rb = tid >> 4, cb = (tid & 15) << 2;
  float acc[4][4] = {};
  for (int kt = 0; kt < HDIM / 16; ++kt) {
    f32x4 av = *(const f32x4*)(A + (ib * 64 + ra) * HDIM + kt * 16 + ca);
    f32x4 bv = *(const f32x4*)(B + (kt * 16 + rb) * HDIM + jb * 64 + cb);
    __syncthreads();
    As[ca + 0][ra] = av[0];
    As[ca + 1][ra] = av[1];
    As[ca + 2][ra] = av[2];
    As[ca + 3][ra] = av[3];
    *(f32x4*)&Bs[rb][cb] = bv;
    __syncthreads();
#pragma unroll
    for (int kk = 0; kk < 16; ++kk) {
      f32x4 a4 = *(const f32x4*)&As[kk][ty << 2];
      f32x4 b4 = *(const f32x4*)&Bs[kk][tx << 2];
#pragma unroll
      for (int u = 0; u < 4; ++u)
#pragma unroll
        for (int v = 0; v < 4; ++v) acc[u][v] = fmaf(a4[u], b4[v], acc[u][v]);
    }
  }
#pragma unroll
  for (int u = 0; u < 4; ++u)
#pragma unroll
    for (int v = 0; v < 4; ++v) {
      int r = ib * 64 + (ty << 2) + u, c = jb * 64 + (tx << 2) + v;
      float val = alpha * acc[u][v];
      if (addI && r == c) val += 1.f;
      C[r * HDIM + c] = val;
    }
}

// ---------------- persistent RNN scan [R17: flag-hint + tag-truth] ----------
// Ledger: R6 flags 2250us | R14 tags+LDS 2670 (poll BW) | R15 direct 5614
// (4x volume) | R16 early-issue 4010 (guaranteed-stale loads, retry BW).
// Decomposition: polls must be CHEAP (4B flag), bulk transfer must happen
// ONCE, after a positive signal. R6 does that but serializes the producer:
// store -> vmcnt(0) ack (~600cy) -> flag store (~600cy). R17 removes the
// drain: flag is a HINT issued right after the data store (raw s_barrier,
// no compiler vmcnt drain); per-dword tags (R14-proven) are the TRUTH.
// Consumer: cheap flag poll -> one 32KB bulk load -> in-register tag check
// -> pend-masked reload of rare stale granules (R16 machinery + sleep).
// Anti-overwrite invariant unchanged (peer can't overwrite my read buffer
// until MY flag advances -> skew <= 1 step); tags only cover the ~1us
// flag-vs-data race window, which detect latency (~1000cy) closes.
__global__ __launch_bounds__(256, 1) void rnn_main(
    const float* __restrict__ xp, const float* __restrict__ Borth,
    const float* __restrict__ W_in, const float* __restrict__ b_mod,
    const float* __restrict__ W_lin, const float* __restrict__ b_lin,
    unsigned* __restrict__ h0, unsigned* __restrict__ h1,
    unsigned* __restrict__ flags, float* __restrict__ out) {
  __shared__ unsigned tile0[8192], tile1[8192];  // 32 KB x 2 (double buffer)

  const int wg = blockIdx.x;
  const int gb = wg & 15;
  const int cg = wg >> 4;
  const int tid = threadIdx.x;
  const int wave = tid >> 6;
  const int lane = tid & 63;
  const int quad = lane >> 4;
  const int l16 = lane & 15;
  const int colg = (cg << 6) + (wave << 4) + l16;           // Bf column
  const int hbase = (cg << 6) + (wave << 4) + (quad << 2);  // epilogue h-col base

  // Borth fragments (round-hi split, R3-proven numerics)
  bf16x8 Bfh[16], Bfl[16];
#pragma unroll
  for (int ki = 0; ki < 16; ++ki) {
#pragma unroll
    for (int j = 0; j < 8; ++j) {
      int k = (ki << 5) + (quad << 3) + j;
      float v = Borth[k * HDIM + colg];
      u16 hb = f2bf(v);
      u16 lb = f2bf(v - bf2f(hb));
      Bfh[ki][j] = __builtin_bit_cast(__bf16, hb);
      Bfl[ki][j] = __builtin_bit_cast(__bf16, lb);
    }
  }
  const f32x4 win4 = *(const f32x4*)(W_in + hbase);
  const f32x4 bm4 = *(const f32x4*)(b_mod + hbase);

  const u64 b0 = (u64)(h0 + (gb << 13));  // 8192 u32 = 32 KB per group
  const u64 b1 = (u64)(h1 + (gb << 13));
  const unsigned vo0 = (unsigned)((tid + 0 * 256) << 4);
  const unsigned vo1 = (unsigned)((tid + 1 * 256) << 4);
  const unsigned vo2 = (unsigned)((tid + 2 * 256) << 4);
  const unsigned vo3 = (unsigned)((tid + 3 * 256) << 4);
  const unsigned vo4 = (unsigned)((tid + 4 * 256) << 4);
  const unsigned vo5 = (unsigned)((tid + 5 * 256) << 4);
  const unsigned vo6 = (unsigned)((tid + 6 * 256) << 4);
  const unsigned vo7 = (unsigned)((tid + 7 * 256) << 4);
  const unsigned soff = (unsigned)(((l16 << 9) + hbase) << 2);  // store byte off
  const unsigned swz = (unsigned)((l16 & 7) << 2);
  unsigned* const myflag = flags + (((gb << 3) + cg) << 5);
  unsigned* const gflags = flags + ((gb << 3) << 5);

  uint4v q0, q1, q2, q3, q4, q5, q6, q7;

#define ISSUE_ALL(B)                                                        \
  asm volatile("global_load_dwordx4 %[q0], %[v0], %[b] sc1\n\t"             \
               "global_load_dwordx4 %[q1], %[v1], %[b] sc1\n\t"             \
               "global_load_dwordx4 %[q2], %[v2], %[b] sc1\n\t"             \
               "global_load_dwordx4 %[q3], %[v3], %[b] sc1\n\t"             \
               "global_load_dwordx4 %[q4], %[v4], %[b] sc1\n\t"             \
               "global_load_dwordx4 %[q5], %[v5], %[b] sc1\n\t"             \
               "global_load_dwordx4 %[q6], %[v6], %[b] sc1\n\t"             \
               "global_load_dwordx4 %[q7], %[v7], %[b] sc1"                 \
               : [q0] "=&v"(q0), [q1] "=&v"(q1), [q2] "=&v"(q2),            \
                 [q3] "=&v"(q3), [q4] "=&v"(q4), [q5] "=&v"(q5),            \
                 [q6] "=&v"(q6), [q7] "=&v"(q7)                             \
               : [v0] "v"(vo0), [v1] "v"(vo1), [v2] "v"(vo2),               \
                 [v3] "v"(vo3), [v4] "v"(vo4), [v5] "v"(vo5),               \
                 [v6] "v"(vo6), [v7] "v"(vo7), [b] "s"(B));
#define CHKG(g)                                                             \
  if (pend & (1u << g)) {                                                   \
    unsigned orv = (q##g[0] ^ rmask) | (q##g[1] ^ rmask) |                  \
                   (q##g[2] ^ rmask) | (q##g[3] ^ rmask);                   \
    if (!(orv & 1u)) pend &= ~(1u << g);                                    \
  }
#define RLDG(g, B)                                                          \
  if (pend & (1u << g))                                                     \
    asm volatile("global_load_dwordx4 %0, %1, %2 sc1"                       \
                 : "=&v"(q##g) : "v"(vo##g), "s"(B));
#define STG(g, q, TL)                                                       \
  {                                                                         \
    int G = tid + ((g) << 8);                                               \
    int r = G >> 7;                                                         \
    unsigned dc = (unsigned)(G & 127) << 2;                                 \
    unsigned phys = ((unsigned)r << 9) | (dc ^ ((unsigned)(r & 7) << 2));   \
    *(uint4v*)(TL + phys) = q;                                              \
  }
#define TAG_POLL(B)                                                         \
  {                                                                         \
    unsigned pend = 0xffu;                                                  \
    int spin = 0;                                                           \
    for (;;) {                                                              \
      asm volatile("s_waitcnt vmcnt(0)" ::: "memory");                      \
      __builtin_amdgcn_sched_barrier(0); /* rule #18 */                     \
      CHKG(0) CHKG(1) CHKG(2) CHKG(3) CHKG(4) CHKG(5) CHKG(6) CHKG(7)       \
      if (!pend) break;                                                     \
      if (++spin > (1 << 11)) break; /* diagnosability valve */             \
      __builtin_amdgcn_s_sleep(1);                                          \
      RLDG(0, B) RLDG(1, B) RLDG(2, B) RLDG(3, B)                           \
      RLDG(4, B) RLDG(5, B) RLDG(6, B) RLDG(7, B)                           \
    }                                                                       \
  }
#define FLAG_WAIT(TGT)                                                      \
  {                                                                         \
    int fspin = 0;                                                          \
    for (;;) {                                                              \
      unsigned fl = __hip_atomic_load(gflags + ((lane & 7) << 5),           \
                                      __ATOMIC_RELAXED,                     \
                                      __HIP_MEMORY_SCOPE_AGENT);            \
      if (__ballot(fl >= (TGT)) == ~0ull) break;                            \
      __builtin_amdgcn_s_sleep(1);                                          \
      if (++fspin > (1 << 13)) break; /* bounded valve */                   \
    }                                                                       \
    __builtin_amdgcn_sched_barrier(0);                                      \
  }

  for (int t = 0; t < TSTEPS; ++t) {
    const u64 rb = (t & 1) ? b1 : b0;
    const u64 wb = (t & 1) ? b0 : b1;
    const unsigned rmask = ((t >> 1) & 1) ? 0xFFFFFFFFu : 0u;
    const unsigned wtag = (unsigned)(((t + 1) >> 1) & 1);
    unsigned* const tl = (t & 1) ? tile1 : tile0;

    const float xs = xp[t * BATCH + (gb << 4) + l16];  // hides under flag wait

    // ---- cheap flag wait (hint): peers have finished step t-1 ----
    if (t) FLAG_WAIT((unsigned)t)

    // ---- one bulk 32KB load + in-register tag validation ----
    ISSUE_ALL(rb)
    TAG_POLL(rb)

    // ---- LDS stage (swizzled: phys = row<<9 | (dcol ^ ((row&7)<<2))) ----
    STG(0, q0, tl) STG(1, q1, tl) STG(2, q2, tl) STG(3, q3, tl)
    STG(4, q4, tl) STG(5, q5, tl) STG(6, q6, tl) STG(7, q7, tl)
    __syncthreads();

    // ---- fragment reads + perm hi/lo split + swapped split-bf16 MFMA ----
    // second granule at (dc0+4)^swz [R14 fix, proven]
    f32x4 hh = {0.f, 0.f, 0.f, 0.f};
    f32x4 lh = {0.f, 0.f, 0.f, 0.f};
    f32x4 hl = {0.f, 0.f, 0.f, 0.f};
#pragma unroll
    for (int ki = 0; ki < 16; ++ki) {
      unsigned dc0 = (unsigned)((ki << 5) + (quad << 3));
      unsigned base = (unsigned)l16 << 9;
      unsigned offL = base + (dc0 ^ swz);
      unsigned offH = base + ((dc0 + 4) ^ swz);
      uint4v e0 = *(const uint4v*)(tl + offL);
      uint4v e1 = *(const uint4v*)(tl + offH);
      uint4v ahv, alv;
      ahv[0] = __builtin_amdgcn_perm(e0[1], e0[0], 0x07060302u);
      ahv[1] = __builtin_amdgcn_perm(e0[3], e0[2], 0x07060302u);
      ahv[2] = __builtin_amdgcn_perm(e1[1], e1[0], 0x07060302u);
      ahv[3] = __builtin_amdgcn_perm(e1[3], e1[2], 0x07060302u);
      alv[0] = __builtin_amdgcn_perm(e0[1], e0[0], 0x05040100u);
      alv[1] = __builtin_amdgcn_perm(e0[3], e0[2], 0x05040100u);
      alv[2] = __builtin_amdgcn_perm(e1[1], e1[0], 0x05040100u);
      alv[3] = __builtin_amdgcn_perm(e1[3], e1[2], 0x05040100u);
      bf16x8 ah = __builtin_bit_cast(bf16x8, ahv);
      bf16x8 al = __builtin_bit_cast(bf16x8, alv);
      hh = __builtin_amdgcn_mfma_f32_16x16x32_bf16(Bfh[ki], ah, hh, 0, 0, 0);
      lh = __builtin_amdgcn_mfma_f32_16x16x32_bf16(Bfh[ki], al, lh, 0, 0, 0);
      hl = __builtin_amdgcn_mfma_f32_16x16x32_bf16(Bfl[ki], ah, hl, 0, 0, 0);
    }

    // ---- epilogue: D = pre^T; ONE packed dwordx4 store (tagged) ----
    {
      uint4v sv;
#pragma unroll
      for (int r = 0; r < 4; ++r) {
        float pre = hh[r] + lh[r] + hl[r] + xs * win4[r];
        float mm = fmaxf(fabsf(pre) + bm4[r], 0.f);
        float hv = (pre > 0.f) ? mm : ((pre < 0.f) ? -mm : 0.f);
        u16 hbv = f2bf(hv);
        u16 lbv = f2bf(hv - bf2f(hbv));
        sv[r] = ((unsigned)hbv << 16) | (unsigned)((lbv & 0xFFFEu) | wtag);
      }
      asm volatile("global_store_dwordx4 %[o], %[d], %[b] sc1" ::[o] "v"(soff),
                   [d] "v"(sv), [b] "s"(wb));
    }

    // ---- flag hint: raw barrier (NO vmcnt drain -- the whole point),
    // then publish. All 256 threads have ISSUED their stores; arrival is
    // covered by tags on the consumer side.
    asm volatile("s_barrier" ::: "memory");
    if (tid == 0)
      __hip_atomic_store(myflag, (unsigned)(t + 1), __ATOMIC_RELAXED,
                         __HIP_MEMORY_SCOPE_AGENT);
  }

  // ---- head: h_784 in b0 (tag 0); flag-gated like any step ----
  if (cg == 0) {
    FLAG_WAIT((unsigned)TSTEPS)
    const unsigned rmask = 0u;
    ISSUE_ALL(b0)
    TAG_POLL(b0)
    STG(0, q0, tile0) STG(1, q1, tile0) STG(2, q2, tile0) STG(3, q3, tile0)
    STG(4, q4, tile0) STG(5, q5, tile0) STG(6, q6, tile0) STG(7, q7, tile0)
    __syncthreads();
    int row = tid >> 4;
    int cls = tid & 15;
    if (cls < NCLS) {
      float acc = b_lin[cls];
      const float* wl = W_lin + cls * HDIM;
      for (int k = 0; k < HDIM; ++k) {
        unsigned phys = ((unsigned)row << 9) |
                        ((unsigned)k ^ (((unsigned)row & 7) << 2));
        unsigned x = tile0[phys];
        float hv = bf2f(x >> 16) + bf2f(x & 0xFFFFu);
        acc = fmaf(hv, wl[k], acc);
      }
      out[((gb << 4) + row) * NCLS + cls] = acc;
    }
  }
}

extern "C" void kernel_launch(void* const* d_in, const int* in_sizes, int n_in,
                              void* d_out, int out_size, void* d_ws, size_t ws_size,
                              hipStream_t stream) {
  const float* inputs = (const float*)d_in[0];  // 256x784
  const int* perm = (const int*)d_in[1];        // 784 (int64 -> int32 by harness)
  const float* W_skew = (const float*)d_in[2];  // 512x512
  const float* W_in = (const float*)d_in[3];    // 512
  const float* b_mod = (const float*)d_in[4];   // 512
  const float* W_lin = (const float*)d_in[5];   // 10x512
  const float* b_lin = (const float*)d_in[6];   // 10
  float* out = (float*)d_out;

  char* ws = (char*)d_ws;
  unsigned* flags = (unsigned*)ws;            // 32 KB (step flags)
  unsigned* h0 = (unsigned*)(ws + 32768);     // 512 KB (packed hi|lo u32)
  unsigned* h1 = h0 + BATCH * HDIM;           // 512 KB
  float* xp = (float*)(h1 + BATCH * HDIM);    // 0.77 MB
  float* X = xp + TSTEPS * BATCH;             // 1 MB
  float* P = X + HDIM * HDIM;                 // 1 MB
  float* Q = P + HDIM * HDIM;                 // 1 MB (total ~4.8 MB)

  // h0 = zeros, tag bit 0 -> valid for t=0 (h0 IS zero).
  // h1 = 0x01010101 -> tag bit 1 = INVALID for first read (t=1 expects 0).
  hipMemsetAsync(flags, 0, 32768, stream);
  hipMemsetAsync(h0, 0, (size_t)BATCH * HDIM * 4, stream);
  hipMemsetAsync(h1, 0x01, (size_t)BATCH * HDIM * 4, stream);

  gather_xp<<<TSTEPS, 256, 0, stream>>>(inputs, perm, xp);
  build_X<<<(HDIM * HDIM) / 256, 256, 0, stream>>>(W_skew, X);

  // expm(A) = (T6(A/32))^(2^5), Horner -- fp32 gemm512 [R2-R8 proven numerics]
  axpyI<<<(HDIM * HDIM) / 256, 256, 0, stream>>>(P, X, 1.f / 6.f);
  float* a = P;
  float* b = Q;
  for (int k = 5; k >= 1; --k) {
    gemm512<<<dim3(8, 8), dim3(16, 16), 0, stream>>>(b, X, a, 1.f / (float)k, 1);
    float* tmp = a; a = b; b = tmp;
  }
  for (int i = 0; i < 5; ++i) {
    gemm512<<<dim3(8, 8), dim3(16, 16), 0, stream>>>(b, a, a, 1.f, 0);
    float* tmp = a; a = b; b = tmp;
  }
  // a == P (10 swaps -> back to P)

  rnn_main<<<NGRP * WGPG, 256, 0, stream>>>(xp, a, W_in, b_mod, W_lin, b_lin,
                                            h0, h1, flags, out);
  (void)in_sizes; (void)n_in; (void)out_size; (void)ws_size;
}